// Round 1
// baseline (2933.623 us; speedup 1.0000x reference)
//
#include <hip/hip_runtime.h>
#include <stdint.h>

#define NB 8
#define NN 4096
#define NC 64
#define NS 1024
#define NK 32
#define NQ (NB*NS)        /* 8192 queries */
#define NP (NQ*NK)        /* 262144 positions */
#define NSL 8             /* knn slices */
#define SLS (NN/NSL)      /* 512 candidates per slice */
#define EPSBN 1e-5f

typedef unsigned long long u64;

__device__ __forceinline__ float lrelu(float x){ return x >= 0.0f ? x : 0.1f*x; }

// IEEE-total-order key: ascending key == ascending float
__device__ __forceinline__ unsigned int fkey(float d){
    unsigned int fb = __float_as_uint(d);
    return (fb & 0x80000000u) ? ~fb : (fb | 0x80000000u);
}

// ---------------------------------------------------------------------------
// FPS: one block per batch. xyz staged in LDS; 1024 threads x 4 points.
// Bit-exact vs numpy: rn-ops (no fma), ((dx2+dy2)+dz2), min, argmax first-occ.
// ---------------------------------------------------------------------------
__global__ __launch_bounds__(1024) void fps_kernel(const float* __restrict__ xyz,
                                                   float* __restrict__ out0,
                                                   float* __restrict__ nxyz)
{
    __shared__ float sX[NN], sY[NN], sZ[NN];
    __shared__ float redV[2][16];
    __shared__ int   redI[2][16];
    const int b = blockIdx.x, t = threadIdx.x;
    const int lane = t & 63, wid = t >> 6;
    const float* base = xyz + (size_t)b*NN*3;
    for (int i = t; i < NN; i += 1024){
        sX[i] = base[3*i]; sY[i] = base[3*i+1]; sZ[i] = base[3*i+2];
    }
    __syncthreads();
    float d0 = 1e10f, d1 = 1e10f, d2 = 1e10f, d3 = 1e10f;
    int far = 0;
    for (int s = 0; s < NS; ++s){
        const float cx = sX[far], cy = sY[far], cz = sZ[far];
        if (t == 0){
            float* npq = nxyz + ((size_t)b*NS + s)*3;
            npq[0] = cx; npq[1] = cy; npq[2] = cz;
            out0[(b*3+0)*NS + s] = cx;
            out0[(b*3+1)*NS + s] = cy;
            out0[(b*3+2)*NS + s] = cz;
        }
        float best; int bidx;
        {
            float dx = __fsub_rn(sX[t], cx), dy = __fsub_rn(sY[t], cy), dz = __fsub_rn(sZ[t], cz);
            float dd = __fadd_rn(__fadd_rn(__fmul_rn(dx,dx), __fmul_rn(dy,dy)), __fmul_rn(dz,dz));
            d0 = fminf(d0, dd); best = d0; bidx = t;
        }
        {
            const int i = t + 1024;
            float dx = __fsub_rn(sX[i], cx), dy = __fsub_rn(sY[i], cy), dz = __fsub_rn(sZ[i], cz);
            float dd = __fadd_rn(__fadd_rn(__fmul_rn(dx,dx), __fmul_rn(dy,dy)), __fmul_rn(dz,dz));
            d1 = fminf(d1, dd);
            if (d1 > best){ best = d1; bidx = i; }
        }
        {
            const int i = t + 2048;
            float dx = __fsub_rn(sX[i], cx), dy = __fsub_rn(sY[i], cy), dz = __fsub_rn(sZ[i], cz);
            float dd = __fadd_rn(__fadd_rn(__fmul_rn(dx,dx), __fmul_rn(dy,dy)), __fmul_rn(dz,dz));
            d2 = fminf(d2, dd);
            if (d2 > best){ best = d2; bidx = i; }
        }
        {
            const int i = t + 3072;
            float dx = __fsub_rn(sX[i], cx), dy = __fsub_rn(sY[i], cy), dz = __fsub_rn(sZ[i], cz);
            float dd = __fadd_rn(__fadd_rn(__fmul_rn(dx,dx), __fmul_rn(dy,dy)), __fmul_rn(dz,dz));
            d3 = fminf(d3, dd);
            if (d3 > best){ best = d3; bidx = i; }
        }
        #pragma unroll
        for (int m = 1; m < 64; m <<= 1){
            float ov = __shfl_xor(best, m);
            int   oi = __shfl_xor(bidx, m);
            if (ov > best || (ov == best && oi < bidx)){ best = ov; bidx = oi; }
        }
        const int par = s & 1;
        if (lane == 0){ redV[par][wid] = best; redI[par][wid] = bidx; }
        __syncthreads();
        float v  = (lane < 16) ? redV[par][lane] : -1e30f;
        int   vi = (lane < 16) ? redI[par][lane] : 0x7fffffff;
        #pragma unroll
        for (int m = 1; m < 16; m <<= 1){
            float ov = __shfl_xor(v, m);
            int   oi = __shfl_xor(vi, m);
            if (ov > v || (ov == v && oi < vi)){ v = ov; vi = oi; }
        }
        far = __shfl(vi, 0);
    }
}

// ---------------------------------------------------------------------------
// KNN stage 1: per (query, slice-of-512) exact top-32 via per-lane tournament
// tree in LDS. Packed node: key(32b)<<17 | cand_idx(12b)<<5 | leafpos(5b).
// Max at root = eviction victim (ties -> larger idx evicted, exact top_k set).
// ---------------------------------------------------------------------------
__global__ __launch_bounds__(64) void knn1_kernel(const float* __restrict__ xyz,
                                                  const float* __restrict__ nxyz,
                                                  u64* __restrict__ cand)
{
    __shared__ float sX[SLS], sY[SLS], sZ[SLS], sP[SLS];
    __shared__ u64 sTree[63*64];
    const int t  = threadIdx.x;
    const int qg = blockIdx.x >> 3;
    const int sl = blockIdx.x & 7;
    const int q  = qg*64 + t;
    const int b  = q >> 10;
    const int j0 = sl * SLS;
    const float* base = xyz + ((size_t)b*NN + j0)*3;
    for (int i = t; i < SLS; i += 64){
        float x = base[3*i], y = base[3*i+1], z = base[3*i+2];
        sX[i] = x; sY[i] = y; sZ[i] = z;
        sP[i] = __fadd_rn(__fadd_rn(__fmul_rn(x,x), __fmul_rn(y,y)), __fmul_rn(z,z));
    }
    // init per-thread tree: leaves = +inf key
    #pragma unroll
    for (int e = 0; e < 32; ++e) sTree[(31+e)*64 + t] = (0xFFFFFFFFull<<17) | (u64)e;
    #pragma unroll
    for (int n = 31; n >= 1; --n){
        u64 a = sTree[(2*n-1)*64 + t], c = sTree[(2*n)*64 + t];
        sTree[(n-1)*64 + t] = (a > c) ? a : c;
    }
    __syncthreads();
    const float* qp = nxyz + (size_t)q*3;
    const float qx = qp[0], qy = qp[1], qz = qp[2];
    const float qsq = __fadd_rn(__fadd_rn(__fmul_rn(qx,qx), __fmul_rn(qy,qy)), __fmul_rn(qz,qz));
    u64 root = sTree[0*64 + t];
    unsigned int cmaxkb = (unsigned int)(root >> 17);
    int rootpos = (int)(root & 31ull);
    #pragma unroll 4
    for (int i = 0; i < SLS; ++i){
        float xj = sX[i], yj = sY[i], zj = sZ[i], pj = sP[i];
        float dot = __fadd_rn(__fadd_rn(__fmul_rn(qx,xj), __fmul_rn(qy,yj)), __fmul_rn(qz,zj));
        float d = __fadd_rn(__fadd_rn(__fmul_rn(-2.0f,dot), qsq), pj);
        unsigned int kb = fkey(d);
        if (kb < cmaxkb){   // strict: ties keep earlier index (matches top_k)
            const int jg = j0 + i;
            u64 v = ((u64)kb << 17) | ((u64)jg << 5) | (u64)rootpos;
            int n = 32 + rootpos;
            sTree[(n-1)*64 + t] = v;
            u64 cur = v;
            #pragma unroll
            for (int l = 0; l < 5; ++l){
                u64 sv = sTree[((n^1)-1)*64 + t];
                if (sv > cur) cur = sv;
                n >>= 1;
                sTree[(n-1)*64 + t] = cur;
            }
            cmaxkb  = (unsigned int)(cur >> 17);
            rootpos = (int)(cur & 31ull);
        }
    }
    u64* op = cand + (size_t)(sl*32)*NQ + q;
    #pragma unroll
    for (int e = 0; e < 32; ++e) op[(size_t)e*NQ] = sTree[(31+e)*64 + t];
}

// ---------------------------------------------------------------------------
// KNN stage 2: merge 8x32 slice candidates -> exact global top-32 per query.
// Lexicographic (key, idx) compare since slice order != index order.
// ---------------------------------------------------------------------------
__global__ __launch_bounds__(64) void knn2_kernel(const u64* __restrict__ cand,
                                                  int* __restrict__ kidx)
{
    __shared__ u64 sTree[63*64];
    const int t = threadIdx.x;
    const int q = blockIdx.x*64 + t;
    #pragma unroll
    for (int e = 0; e < 32; ++e) sTree[(31+e)*64 + t] = (0xFFFFFFFFull<<17) | (u64)e;
    #pragma unroll
    for (int n = 31; n >= 1; --n){
        u64 a = sTree[(2*n-1)*64 + t], c = sTree[(2*n)*64 + t];
        sTree[(n-1)*64 + t] = (a > c) ? a : c;
    }
    u64 root = sTree[0*64 + t];
    u64 rootcmp = root >> 5;
    int rootpos = (int)(root & 31ull);
    #pragma unroll 4
    for (int i = 0; i < NSL*32; ++i){
        u64 cv = cand[(size_t)i*NQ + q];
        if ((cv >> 5) < rootcmp){
            u64 v = ((cv >> 5) << 5) | (u64)rootpos;
            int n = 32 + rootpos;
            sTree[(n-1)*64 + t] = v;
            u64 cur = v;
            #pragma unroll
            for (int l = 0; l < 5; ++l){
                u64 sv = sTree[((n^1)-1)*64 + t];
                if (sv > cur) cur = sv;
                n >>= 1;
                sTree[(n-1)*64 + t] = cur;
            }
            rootcmp = cur >> 5;
            rootpos = (int)(cur & 31ull);
        }
    }
    int* op = kidx + (size_t)q*NK;
    #pragma unroll
    for (int e = 0; e < 32; ++e) op[e] = (int)((sTree[(31+e)*64 + t] >> 5) & 0xFFFull);
}

// ---------------------------------------------------------------------------
// Gather: x0[c][p] = features[b, kidx[p], c]   (layout [C, NP])
// ---------------------------------------------------------------------------
__global__ __launch_bounds__(256) void gather_kernel(const float* __restrict__ features,
                                                     const int* __restrict__ kidx,
                                                     float* __restrict__ x0)
{
    const int p = blockIdx.x*256 + threadIdx.x;
    const int b = p >> 15;
    const int idx = kidx[p];
    const float4* f = (const float4*)(features + ((size_t)b*NN + idx)*NC);
    #pragma unroll
    for (int c4 = 0; c4 < 16; ++c4){
        float4 v = f[c4];
        x0[(size_t)(4*c4+0)*NP + p] = v.x;
        x0[(size_t)(4*c4+1)*NP + p] = v.y;
        x0[(size_t)(4*c4+2)*NP + p] = v.z;
        x0[(size_t)(4*c4+3)*NP + p] = v.w;
    }
}

// ---------------------------------------------------------------------------
// Conv 1x1 (+ optional folded BN-affine + leaky on INPUT) + fused stats.
// in/out layout [C, NP]. partials: [1024 blocks][128] (sum[64], sumsq[64]).
// ---------------------------------------------------------------------------
__global__ __launch_bounds__(256) void conv_bn_kernel(const float* __restrict__ in,
    float* __restrict__ out, const float* __restrict__ W, const float* __restrict__ bias,
    const float* __restrict__ aff, float* __restrict__ partials, const int apply_act)
{
    __shared__ __align__(16) float sWt[64*64];   // [c][o]
    __shared__ float sSc[64], sSh[64], sB[64];
    __shared__ float sRed[4*128];
    const int t = threadIdx.x;
    for (int i = t; i < 4096; i += 256){
        int o = i >> 6, c = i & 63;
        sWt[c*64 + o] = W[o*64 + c];
    }
    if (t < 64){
        sB[t] = bias[t];
        if (apply_act){ sSc[t] = aff[t]; sSh[t] = aff[64+t]; }
        else          { sSc[t] = 1.0f;  sSh[t] = 0.0f; }
    }
    __syncthreads();
    const int p = blockIdx.x*256 + t;
    float acc[64];
    #pragma unroll
    for (int o = 0; o < 64; ++o) acc[o] = sB[o];
    #pragma unroll 4
    for (int c = 0; c < 64; ++c){
        float xv = in[(size_t)c*NP + p];
        if (apply_act){
            xv = fmaf(sSc[c], xv, sSh[c]);
            xv = xv >= 0.0f ? xv : 0.1f*xv;
        }
        const float4* wr = (const float4*)(sWt + c*64);
        #pragma unroll
        for (int o4 = 0; o4 < 16; ++o4){
            float4 w = wr[o4];
            acc[4*o4+0] = fmaf(w.x, xv, acc[4*o4+0]);
            acc[4*o4+1] = fmaf(w.y, xv, acc[4*o4+1]);
            acc[4*o4+2] = fmaf(w.z, xv, acc[4*o4+2]);
            acc[4*o4+3] = fmaf(w.w, xv, acc[4*o4+3]);
        }
    }
    #pragma unroll
    for (int o = 0; o < 64; ++o) out[(size_t)o*NP + p] = acc[o];
    const int lane = t & 63, wid = t >> 6;
    #pragma unroll
    for (int o = 0; o < 64; ++o){
        float v = acc[o], v2 = v*v;
        #pragma unroll
        for (int m = 1; m < 64; m <<= 1){
            v  += __shfl_xor(v,  m);
            v2 += __shfl_xor(v2, m);
        }
        if (lane == 0){ sRed[wid*128 + o] = v; sRed[wid*128 + 64 + o] = v2; }
    }
    __syncthreads();
    if (t < 128){
        float s = sRed[t] + sRed[128+t] + sRed[256+t] + sRed[384+t];
        partials[(size_t)blockIdx.x*128 + t] = s;
    }
}

// ---------------------------------------------------------------------------
// Finalize BN stats -> per-channel affine: scale = g*rsqrt(var+eps),
// shift = beta - mean*scale.
// ---------------------------------------------------------------------------
__global__ __launch_bounds__(512) void finalize_kernel(const float* __restrict__ partials,
    const float* __restrict__ g, const float* __restrict__ beta, float* __restrict__ aff)
{
    __shared__ float l1[512];
    __shared__ float lS[128];
    const int t = threadIdx.x;
    const int stat = t & 127, qq = t >> 7;
    float s = 0.0f;
    #pragma unroll 4
    for (int r = qq*256; r < qq*256 + 256; ++r) s += partials[(size_t)r*128 + stat];
    l1[t] = s;
    __syncthreads();
    if (t < 128) lS[t] = l1[t] + l1[128+t] + l1[256+t] + l1[384+t];
    __syncthreads();
    if (t < 64){
        float S1 = lS[t], S2 = lS[64+t];
        float mean = S1 * (1.0f/(float)NP);
        float var  = fmaxf(S2 * (1.0f/(float)NP) - mean*mean, 0.0f);
        float sc = g[t] * rsqrtf(var + EPSBN);
        aff[t]    = sc;
        aff[64+t] = beta[t] - mean*sc;
    }
}

// ---------------------------------------------------------------------------
// Residual: x2 = leaky(affV(v) + leaky(affY(yt)))   (float4 elementwise)
// ---------------------------------------------------------------------------
__global__ __launch_bounds__(256) void resid_kernel(const float* __restrict__ v,
    const float* __restrict__ yt, float* __restrict__ x2,
    const float* __restrict__ affV, const float* __restrict__ affY)
{
    const size_t e = (size_t)blockIdx.x*256 + threadIdx.x;
    const int c = (int)(e >> 16);    // NP/4 = 65536 float4 per channel
    const float va = affV[c], vb = affV[64+c];
    const float ya = affY[c], yb = affY[64+c];
    const float4 vv = ((const float4*)v)[e];
    const float4 yy = ((const float4*)yt)[e];
    float4 r;
    r.x = lrelu(fmaf(va, vv.x, vb) + lrelu(fmaf(ya, yy.x, yb)));
    r.y = lrelu(fmaf(va, vv.y, vb) + lrelu(fmaf(ya, yy.y, yb)));
    r.z = lrelu(fmaf(va, vv.z, vb) + lrelu(fmaf(ya, yy.z, yb)));
    r.w = lrelu(fmaf(va, vv.w, vb) + lrelu(fmaf(ya, yy.w, yb)));
    ((float4*)x2)[e] = r;
}

// ---------------------------------------------------------------------------
// Final: x3 = leaky(aff(v2) + x2); out1[b,c,s] = max_k x3
// ---------------------------------------------------------------------------
__global__ __launch_bounds__(256) void final_kernel(const float* __restrict__ v2,
    const float* __restrict__ x2, const float* __restrict__ aff, float* __restrict__ out1)
{
    const int gg = blockIdx.x*256 + threadIdx.x;   // c*8192 + bs
    const int c = gg >> 13;
    const int bs = gg & 8191;
    const float a = aff[c], sh = aff[64+c];
    const float4* pv = (const float4*)(v2 + (size_t)c*NP + (size_t)bs*NK);
    const float4* px = (const float4*)(x2 + (size_t)c*NP + (size_t)bs*NK);
    float m = -3.0e38f;
    #pragma unroll
    for (int i = 0; i < 8; ++i){
        float4 av = pv[i], xv = px[i];
        m = fmaxf(m, lrelu(fmaf(a, av.x, sh) + xv.x));
        m = fmaxf(m, lrelu(fmaf(a, av.y, sh) + xv.y));
        m = fmaxf(m, lrelu(fmaf(a, av.z, sh) + xv.z));
        m = fmaxf(m, lrelu(fmaf(a, av.w, sh) + xv.w));
    }
    const int b = bs >> 10, s = bs & 1023;
    out1[((size_t)b*NC + c)*NS + s] = m;
}

// ---------------------------------------------------------------------------
extern "C" void kernel_launch(void* const* d_in, const int* in_sizes, int n_in,
                              void* d_out, int out_size, void* d_ws, size_t ws_size,
                              hipStream_t stream)
{
    const float* xyz      = (const float*)d_in[0];
    const float* features = (const float*)d_in[1];
    const float* w_t    = (const float*)d_in[2];
    const float* w1_0   = (const float*)d_in[3];
    const float* w2_0   = (const float*)d_in[4];
    const float* w1_1   = (const float*)d_in[5];
    const float* w2_1   = (const float*)d_in[6];
    const float* b_t    = (const float*)d_in[7];
    const float* b1_0   = (const float*)d_in[8];
    const float* b2_0   = (const float*)d_in[9];
    const float* b1_1   = (const float*)d_in[10];
    const float* b2_1   = (const float*)d_in[11];
    const float* g_t    = (const float*)d_in[12];
    const float* g1_0   = (const float*)d_in[13];
    const float* g2_0   = (const float*)d_in[14];
    const float* g1_1   = (const float*)d_in[15];
    const float* g2_1   = (const float*)d_in[16];
    const float* beta_t  = (const float*)d_in[17];
    const float* beta1_0 = (const float*)d_in[18];
    const float* beta2_0 = (const float*)d_in[19];
    const float* beta1_1 = (const float*)d_in[20];
    const float* beta2_1 = (const float*)d_in[21];

    float* out = (float*)d_out;

    // workspace layout (u64 cand first for alignment)
    u64*   cand  = (u64*)d_ws;                                   // 256*NQ u64 = 16 MB
    float* buf0  = (float*)((char*)d_ws + (size_t)256*NQ*sizeof(u64));
    float* buf1  = buf0 + (size_t)NC*NP;
    float* buf2  = buf1 + (size_t)NC*NP;
    float* nxyz  = buf2 + (size_t)NC*NP;                         // NB*NS*3
    int*   kidx  = (int*)(nxyz + (size_t)NB*NS*3);               // NP ints
    float* partials = (float*)(kidx + NP);                       // 1024*128
    float* affx  = partials + 1024*128;                          // 5*128

    fps_kernel<<<NB, 1024, 0, stream>>>(xyz, out, nxyz);
    knn1_kernel<<<(NQ/64)*NSL, 64, 0, stream>>>(xyz, nxyz, cand);
    knn2_kernel<<<NQ/64, 64, 0, stream>>>(cand, kidx);
    gather_kernel<<<NP/256, 256, 0, stream>>>(features, kidx, buf0);

    // stage t
    conv_bn_kernel<<<NP/256, 256, 0, stream>>>(buf0, buf1, w_t, b_t, nullptr, partials, 0);
    finalize_kernel<<<1, 512, 0, stream>>>(partials, g_t, beta_t, affx + 0);
    // resblock 0
    conv_bn_kernel<<<NP/256, 256, 0, stream>>>(buf1, buf0, w1_0, b1_0, affx + 0, partials, 1);
    finalize_kernel<<<1, 512, 0, stream>>>(partials, g1_0, beta1_0, affx + 128);
    conv_bn_kernel<<<NP/256, 256, 0, stream>>>(buf0, buf2, w2_0, b2_0, affx + 128, partials, 1);
    finalize_kernel<<<1, 512, 0, stream>>>(partials, g2_0, beta2_0, affx + 256);
    resid_kernel<<<(NC*NP/4)/256, 256, 0, stream>>>(buf2, buf1, buf0, affx + 256, affx + 0);
    // resblock 1
    conv_bn_kernel<<<NP/256, 256, 0, stream>>>(buf0, buf1, w1_1, b1_1, nullptr, partials, 0);
    finalize_kernel<<<1, 512, 0, stream>>>(partials, g1_1, beta1_1, affx + 384);
    conv_bn_kernel<<<NP/256, 256, 0, stream>>>(buf1, buf2, w2_1, b2_1, affx + 384, partials, 1);
    finalize_kernel<<<1, 512, 0, stream>>>(partials, g2_1, beta2_1, affx + 512);
    // epilogue: residual + max over K
    final_kernel<<<(NC*NQ)/256, 256, 0, stream>>>(buf2, buf0, affx + 512, out + (size_t)NB*3*NS);
}

// Round 2
// 2218.861 us; speedup vs baseline: 1.3221x; 1.3221x over previous
//
#include <hip/hip_runtime.h>
#include <stdint.h>

#define NB 8
#define NN 4096
#define NC 64
#define NS 1024
#define NK 32
#define NQ (NB*NS)        /* 8192 queries */
#define NP (NQ*NK)        /* 262144 positions */
#define EPSBN 1e-5f

typedef unsigned long long u64;

__device__ __forceinline__ float lrelu(float x){ return x >= 0.0f ? x : 0.1f*x; }

// IEEE-total-order key: ascending key == ascending float (for our values >= 0)
__device__ __forceinline__ unsigned int fkey(float d){
    unsigned int fb = __float_as_uint(d);
    return (fb & 0x80000000u) ? ~fb : (fb | 0x80000000u);
}

// ---- DPP wave(64) helpers -------------------------------------------------
// max-reduce: result broadcast to all lanes (via readlane 63)
__device__ __forceinline__ float wave_max_f(float x){
    int v = __float_as_int(x);
    {int o=__builtin_amdgcn_update_dpp(v,v,0x111,0xf,0xf,false); v=__float_as_int(fmaxf(__int_as_float(v),__int_as_float(o)));}
    {int o=__builtin_amdgcn_update_dpp(v,v,0x112,0xf,0xf,false); v=__float_as_int(fmaxf(__int_as_float(v),__int_as_float(o)));}
    {int o=__builtin_amdgcn_update_dpp(v,v,0x114,0xf,0xf,false); v=__float_as_int(fmaxf(__int_as_float(v),__int_as_float(o)));}
    {int o=__builtin_amdgcn_update_dpp(v,v,0x118,0xf,0xf,false); v=__float_as_int(fmaxf(__int_as_float(v),__int_as_float(o)));}
    {int o=__builtin_amdgcn_update_dpp(v,v,0x142,0xf,0xf,false); v=__float_as_int(fmaxf(__int_as_float(v),__int_as_float(o)));}
    {int o=__builtin_amdgcn_update_dpp(v,v,0x143,0xf,0xf,false); v=__float_as_int(fmaxf(__int_as_float(v),__int_as_float(o)));}
    return __int_as_float(__builtin_amdgcn_readlane(v, 63));
}
// sum-reduce (valid on lane 63 only)
__device__ __forceinline__ float wave_sum_f(float x){
    int v = __float_as_int(x);
    {int o=__builtin_amdgcn_update_dpp(0,v,0x111,0xf,0xf,true); v=__float_as_int(__int_as_float(v)+__int_as_float(o));}
    {int o=__builtin_amdgcn_update_dpp(0,v,0x112,0xf,0xf,true); v=__float_as_int(__int_as_float(v)+__int_as_float(o));}
    {int o=__builtin_amdgcn_update_dpp(0,v,0x114,0xf,0xf,true); v=__float_as_int(__int_as_float(v)+__int_as_float(o));}
    {int o=__builtin_amdgcn_update_dpp(0,v,0x118,0xf,0xf,true); v=__float_as_int(__int_as_float(v)+__int_as_float(o));}
    {int o=__builtin_amdgcn_update_dpp(0,v,0x142,0xf,0xf,true); v=__float_as_int(__int_as_float(v)+__int_as_float(o));}
    {int o=__builtin_amdgcn_update_dpp(0,v,0x143,0xf,0xf,true); v=__float_as_int(__int_as_float(v)+__int_as_float(o));}
    return __int_as_float(v);
}
// inclusive prefix-sum over 64 lanes (ints)
__device__ __forceinline__ int wave_incl_add(int x){
    int v = x;
    {int o=__builtin_amdgcn_update_dpp(0,v,0x111,0xf,0xf,true); v+=o;}
    {int o=__builtin_amdgcn_update_dpp(0,v,0x112,0xf,0xf,true); v+=o;}
    {int o=__builtin_amdgcn_update_dpp(0,v,0x114,0xf,0xf,true); v+=o;}
    {int o=__builtin_amdgcn_update_dpp(0,v,0x118,0xf,0xf,true); v+=o;}
    {int o=__builtin_amdgcn_update_dpp(0,v,0x142,0xa,0xf,true); v+=o;}  // +lane15 -> row1, +lane47 -> row3
    {int o=__builtin_amdgcn_update_dpp(0,v,0x143,0xc,0xf,true); v+=o;}  // +lane31 -> rows 2,3
    return v;
}

// ---------------------------------------------------------------------------
// FPS: one block per batch, 512 threads, 8 contiguous points/thread in REGS.
// Per step: reg update + DPP wave-argmax + packed-u64 8-slot merge, 1 barrier.
// Bit-exact vs numpy: rn ops, ((dx2+dy2)+dz2), fminf, argmax first-occurrence.
// ---------------------------------------------------------------------------
__global__ __launch_bounds__(512) void fps_kernel(const float* __restrict__ xyz,
                                                  float* __restrict__ out0,
                                                  float* __restrict__ nxyz)
{
    __shared__ float sX[NN], sY[NN], sZ[NN];
    __shared__ u64 slots[2][8];
    const int b = blockIdx.x, t = threadIdx.x;
    const int lane = t & 63, wv = t >> 6;
    const float* base = xyz + (size_t)b*NN*3;
    for (int i = t; i < NN; i += 512){
        const float* pp = base + 3*i;
        sX[i] = pp[0]; sY[i] = pp[1]; sZ[i] = pp[2];
    }
    __syncthreads();
    float px[8], py[8], pz[8], dist[8];
    const int pb = t*8;
    #pragma unroll
    for (int j = 0; j < 8; ++j){
        px[j]=sX[pb+j]; py[j]=sY[pb+j]; pz[j]=sZ[pb+j]; dist[j]=1e10f;
    }
    int far = 0;
    for (int s = 0; s < NS; ++s){
        const float cx = sX[far], cy = sY[far], cz = sZ[far];
        if (t == 0){
            float* npq = nxyz + ((size_t)b*NS + s)*3;
            npq[0]=cx; npq[1]=cy; npq[2]=cz;
            out0[(b*3+0)*NS+s]=cx; out0[(b*3+1)*NS+s]=cy; out0[(b*3+2)*NS+s]=cz;
        }
        float best = -1.0f; int bidx = 0;
        #pragma unroll
        for (int j = 0; j < 8; ++j){
            float dx=__fsub_rn(px[j],cx), dy=__fsub_rn(py[j],cy), dz=__fsub_rn(pz[j],cz);
            float dd=__fadd_rn(__fadd_rn(__fmul_rn(dx,dx),__fmul_rn(dy,dy)),__fmul_rn(dz,dz));
            float nd = fminf(dist[j], dd);
            dist[j] = nd;
            if (nd > best){ best = nd; bidx = pb + j; }   // strict >: first-occurrence
        }
        float wmax = wave_max_f(best);
        u64 mask = __ballot(best == wmax);
        int L = __ffsll(mask) - 1;                        // lowest lane = smallest idx
        int widx = __builtin_amdgcn_readlane(bidx, L);
        const int par = s & 1;
        if (lane == 0){
            u64 pk = ((u64)fkey(wmax) << 32) | (u64)(0xFFFFFFFFu - (unsigned)widx);
            slots[par][wv] = pk;
        }
        __syncthreads();
        u64 m = slots[par][0];
        #pragma unroll
        for (int k = 1; k < 8; ++k){ u64 v = slots[par][k]; if (v > m) m = v; }
        far = (int)(0xFFFFFFFFu - (unsigned)(m & 0xFFFFFFFFull));
    }
}

// ---------------------------------------------------------------------------
// KNN: one wave per query; exact top-32 SET via 4-pass radix select on fkey,
// ties at threshold resolved by smallest index (idx = i*64+lane, i-major).
// Order within the 32 is irrelevant downstream (max-pool / sums over K).
// ---------------------------------------------------------------------------
__global__ __launch_bounds__(256) void knn_kernel(const float* __restrict__ xyz,
                                                  const float* __restrict__ nxyz,
                                                  int* __restrict__ kidx)
{
    __shared__ __align__(16) unsigned int hist[4][256];
    const int t = threadIdx.x, lane = t & 63, w = t >> 6;
    const int q = blockIdx.x*4 + w;
    const int b = q >> 10;
    const float* base = xyz + (size_t)b*NN*3;
    const float* qp = nxyz + (size_t)q*3;
    const float qx = qp[0], qy = qp[1], qz = qp[2];
    const float qsq = __fadd_rn(__fadd_rn(__fmul_rn(qx,qx),__fmul_rn(qy,qy)),__fmul_rn(qz,qz));

    unsigned int key[64];
    #pragma unroll
    for (int i = 0; i < 64; ++i){
        const int idx = (i<<6) + lane;
        const float* pp = base + 3*idx;
        float x = pp[0], y = pp[1], z = pp[2];
        float dot = __fadd_rn(__fadd_rn(__fmul_rn(qx,x),__fmul_rn(qy,y)),__fmul_rn(qz,z));
        float psq = __fadd_rn(__fadd_rn(__fmul_rn(x,x),__fmul_rn(y,y)),__fmul_rn(z,z));
        float d = __fadd_rn(__fadd_rn(__fmul_rn(-2.0f,dot),qsq),psq);
        key[i] = fkey(d);
    }

    unsigned int prefix = 0;
    int need = 32;
    #pragma unroll
    for (int pass = 0; pass < 4; ++pass){
        const int shift = 24 - 8*pass;
        *(uint4*)&hist[w][lane*4] = make_uint4(0u,0u,0u,0u);
        __syncthreads();
        #pragma unroll
        for (int i = 0; i < 64; ++i){
            unsigned int k = key[i];
            bool part = (pass == 0) ? true : ((k >> (shift+8)) == prefix);
            if (part) atomicAdd(&hist[w][(k >> shift) & 255u], 1u);
        }
        __syncthreads();
        uint4 hv = *(uint4*)&hist[w][lane*4];
        int lsum = (int)(hv.x + hv.y + hv.z + hv.w);
        int incl = wave_incl_add(lsum);
        int excl = incl - lsum;
        u64 mask = __ballot(incl >= need);
        int L = __ffsll(mask) - 1;
        int ex = __builtin_amdgcn_readlane(excl, L);
        int h0 = __builtin_amdgcn_readlane((int)hv.x, L);
        int h1 = __builtin_amdgcn_readlane((int)hv.y, L);
        int h2 = __builtin_amdgcn_readlane((int)hv.z, L);
        int h3 = __builtin_amdgcn_readlane((int)hv.w, L);
        int D, below;
        if      (ex + h0 >= need)           { D = 0; below = ex; }
        else if (ex + h0 + h1 >= need)      { D = 1; below = ex + h0; }
        else if (ex + h0 + h1 + h2 >= need) { D = 2; below = ex + h0 + h1; }
        else                                { D = 3; below = ex + h0 + h1 + h2; }
        (void)h3;
        prefix = (prefix << 8) | (unsigned)(L*4 + D);
        need -= below;
        __syncthreads();
    }
    const unsigned int T = prefix;

    // emission: all keys < T, plus first `need` keys == T in ascending idx
    int cl = 0;
    #pragma unroll
    for (int i = 0; i < 64; ++i) cl += (key[i] < T) ? 1 : 0;
    int incl_cl = wave_incl_add(cl);
    int clx = incl_cl - cl;
    int tiebase = __builtin_amdgcn_readlane(incl_cl, 63);
    int* oq = kidx + (size_t)q*NK;
    int pos = clx;
    #pragma unroll
    for (int i = 0; i < 64; ++i){
        if (key[i] < T){ oq[pos] = (i<<6) + lane; ++pos; }
    }
    int tcount = 0;
    for (int i = 0; i < 64 && tcount < need; ++i){
        u64 m = __ballot(key[i] == T);
        int myrank = (int)__popcll(m & ((1ull << lane) - 1ull));
        if ((key[i] == T) && (tcount + myrank < need))
            oq[tiebase + tcount + myrank] = (i<<6) + lane;
        tcount += (int)__popcll(m);
    }
}

// ---------------------------------------------------------------------------
// Gather: x0[c][p] = features[b, kidx[p], c]   (layout [C, NP])
// ---------------------------------------------------------------------------
__global__ __launch_bounds__(256) void gather_kernel(const float* __restrict__ features,
                                                     const int* __restrict__ kidx,
                                                     float* __restrict__ x0)
{
    const int p = blockIdx.x*256 + threadIdx.x;
    const int b = p >> 15;
    const int idx = kidx[p];
    const float4* f = (const float4*)(features + ((size_t)b*NN + idx)*NC);
    #pragma unroll
    for (int c4 = 0; c4 < 16; ++c4){
        float4 v = f[c4];
        x0[(size_t)(4*c4+0)*NP + p] = v.x;
        x0[(size_t)(4*c4+1)*NP + p] = v.y;
        x0[(size_t)(4*c4+2)*NP + p] = v.z;
        x0[(size_t)(4*c4+3)*NP + p] = v.w;
    }
}

// ---------------------------------------------------------------------------
// Conv 1x1 (+ optional folded BN-affine + leaky on INPUT). Pure GEMM pass.
// 512 thr: waves 0-3 -> o[0:32), waves 4-7 -> o[32:64); 4 positions/thread.
// LDS weight reads amortized 8x vs naive (8 b128 per 128 lane-fma).
// ---------------------------------------------------------------------------
__global__ __launch_bounds__(512) void conv_kernel(const float* __restrict__ in,
    float* __restrict__ out, const float* __restrict__ W, const float* __restrict__ bias,
    const float* __restrict__ aff, const int apply_act)
{
    __shared__ __align__(16) float sWt[64*64];   // [c][o]
    __shared__ float sSc[64], sSh[64], sB[64];
    const int t = threadIdx.x;
    for (int i = t; i < 4096; i += 512){
        int o = i >> 6, c = i & 63;
        sWt[c*64 + o] = W[i];
    }
    if (t < 64){
        sB[t] = bias[t];
        if (apply_act){ sSc[t] = aff[t]; sSh[t] = aff[64+t]; }
        else          { sSc[t] = 1.0f;  sSh[t] = 0.0f; }
    }
    __syncthreads();
    const int lane = t & 63;
    const int wv = t >> 6;
    const int obase = (wv >> 2) * 32;
    const int p0 = blockIdx.x*1024 + (wv & 3)*64 + lane;
    float acc[4][32];
    #pragma unroll
    for (int o = 0; o < 32; ++o){
        float bb = sB[obase + o];
        acc[0][o]=bb; acc[1][o]=bb; acc[2][o]=bb; acc[3][o]=bb;
    }
    #pragma unroll 8
    for (int c = 0; c < 64; ++c){
        float xv[4];
        xv[0] = in[(size_t)c*NP + p0];
        xv[1] = in[(size_t)c*NP + p0 + 256];
        xv[2] = in[(size_t)c*NP + p0 + 512];
        xv[3] = in[(size_t)c*NP + p0 + 768];
        if (apply_act){
            float sc = sSc[c], sh = sSh[c];
            #pragma unroll
            for (int j = 0; j < 4; ++j){
                float v = fmaf(sc, xv[j], sh);
                xv[j] = v >= 0.0f ? v : 0.1f*v;
            }
        }
        const float4* wr = (const float4*)(sWt + c*64 + obase);
        #pragma unroll
        for (int o4 = 0; o4 < 8; ++o4){
            float4 wvv = wr[o4];
            #pragma unroll
            for (int j = 0; j < 4; ++j){
                acc[j][4*o4+0] = fmaf(wvv.x, xv[j], acc[j][4*o4+0]);
                acc[j][4*o4+1] = fmaf(wvv.y, xv[j], acc[j][4*o4+1]);
                acc[j][4*o4+2] = fmaf(wvv.z, xv[j], acc[j][4*o4+2]);
                acc[j][4*o4+3] = fmaf(wvv.w, xv[j], acc[j][4*o4+3]);
            }
        }
    }
    #pragma unroll
    for (int o = 0; o < 32; ++o){
        float* po = out + (size_t)(obase+o)*NP + p0;
        po[0]   = acc[0][o];
        po[256] = acc[1][o];
        po[512] = acc[2][o];
        po[768] = acc[3][o];
    }
}

// ---------------------------------------------------------------------------
// BN stats: block = (channel, chunk of 8192); coalesced float4, DPP reduce.
// partials[c*32+chunk] = sum ; partials[2048 + c*32+chunk] = sumsq
// ---------------------------------------------------------------------------
__global__ __launch_bounds__(256) void stats_kernel(const float* __restrict__ buf,
                                                    float* __restrict__ partials)
{
    __shared__ float red[8];
    const int t = threadIdx.x, lane = t & 63, wv = t >> 6;
    const int c = blockIdx.x >> 5, chunk = blockIdx.x & 31;
    const float4* p4 = (const float4*)(buf + (size_t)c*NP + (size_t)chunk*8192) + t;
    float s1 = 0.0f, s2 = 0.0f;
    #pragma unroll
    for (int i = 0; i < 8; ++i){
        float4 v = p4[i*256];
        s1 += v.x + v.y + v.z + v.w;
        s2 += v.x*v.x + v.y*v.y + v.z*v.z + v.w*v.w;
    }
    float t1 = wave_sum_f(s1), t2 = wave_sum_f(s2);
    if (lane == 63){ red[wv*2] = t1; red[wv*2+1] = t2; }
    __syncthreads();
    if (t == 0){
        partials[blockIdx.x]        = red[0]+red[2]+red[4]+red[6];
        partials[2048 + blockIdx.x] = red[1]+red[3]+red[5]+red[7];
    }
}

// ---------------------------------------------------------------------------
// Finalize BN stats -> per-channel affine: scale = g*rsqrt(var+eps),
// shift = beta - mean*scale.
// ---------------------------------------------------------------------------
__global__ __launch_bounds__(64) void finalize_kernel(const float* __restrict__ partials,
    const float* __restrict__ g, const float* __restrict__ beta, float* __restrict__ aff)
{
    const int t = threadIdx.x;   // 64 threads, t = channel
    float S1 = 0.0f, S2 = 0.0f;
    #pragma unroll 8
    for (int i = 0; i < 32; ++i){
        S1 += partials[t*32 + i];
        S2 += partials[2048 + t*32 + i];
    }
    float mean = S1 * (1.0f/(float)NP);
    float var  = fmaxf(S2 * (1.0f/(float)NP) - mean*mean, 0.0f);
    float sc = g[t] * rsqrtf(var + EPSBN);
    aff[t]    = sc;
    aff[64+t] = beta[t] - mean*sc;
}

// ---------------------------------------------------------------------------
// Residual: x2 = leaky(affV(v) + leaky(affY(yt)))   (float4 elementwise)
// ---------------------------------------------------------------------------
__global__ __launch_bounds__(256) void resid_kernel(const float* __restrict__ v,
    const float* __restrict__ yt, float* __restrict__ x2,
    const float* __restrict__ affV, const float* __restrict__ affY)
{
    const size_t e = (size_t)blockIdx.x*256 + threadIdx.x;
    const int c = (int)(e >> 16);    // NP/4 = 65536 float4 per channel
    const float va = affV[c], vb = affV[64+c];
    const float ya = affY[c], yb = affY[64+c];
    const float4 vv = ((const float4*)v)[e];
    const float4 yy = ((const float4*)yt)[e];
    float4 r;
    r.x = lrelu(fmaf(va, vv.x, vb) + lrelu(fmaf(ya, yy.x, yb)));
    r.y = lrelu(fmaf(va, vv.y, vb) + lrelu(fmaf(ya, yy.y, yb)));
    r.z = lrelu(fmaf(va, vv.z, vb) + lrelu(fmaf(ya, yy.z, yb)));
    r.w = lrelu(fmaf(va, vv.w, vb) + lrelu(fmaf(ya, yy.w, yb)));
    ((float4*)x2)[e] = r;
}

// ---------------------------------------------------------------------------
// Final: x3 = leaky(aff(v2) + x2); out1[b,c,s] = max_k x3
// ---------------------------------------------------------------------------
__global__ __launch_bounds__(256) void final_kernel(const float* __restrict__ v2,
    const float* __restrict__ x2, const float* __restrict__ aff, float* __restrict__ out1)
{
    const int gg = blockIdx.x*256 + threadIdx.x;   // c*8192 + bs
    const int c = gg >> 13;
    const int bs = gg & 8191;
    const float a = aff[c], sh = aff[64+c];
    const float4* pv = (const float4*)(v2 + (size_t)c*NP + (size_t)bs*NK);
    const float4* px = (const float4*)(x2 + (size_t)c*NP + (size_t)bs*NK);
    float m = -3.0e38f;
    #pragma unroll
    for (int i = 0; i < 8; ++i){
        float4 av = pv[i], xv = px[i];
        m = fmaxf(m, lrelu(fmaf(a, av.x, sh) + xv.x));
        m = fmaxf(m, lrelu(fmaf(a, av.y, sh) + xv.y));
        m = fmaxf(m, lrelu(fmaf(a, av.z, sh) + xv.z));
        m = fmaxf(m, lrelu(fmaf(a, av.w, sh) + xv.w));
    }
    const int b = bs >> 10, s = bs & 1023;
    out1[((size_t)b*NC + c)*NS + s] = m;
}

// ---------------------------------------------------------------------------
extern "C" void kernel_launch(void* const* d_in, const int* in_sizes, int n_in,
                              void* d_out, int out_size, void* d_ws, size_t ws_size,
                              hipStream_t stream)
{
    const float* xyz      = (const float*)d_in[0];
    const float* features = (const float*)d_in[1];
    const float* w_t    = (const float*)d_in[2];
    const float* w1_0   = (const float*)d_in[3];
    const float* w2_0   = (const float*)d_in[4];
    const float* w1_1   = (const float*)d_in[5];
    const float* w2_1   = (const float*)d_in[6];
    const float* b_t    = (const float*)d_in[7];
    const float* b1_0   = (const float*)d_in[8];
    const float* b2_0   = (const float*)d_in[9];
    const float* b1_1   = (const float*)d_in[10];
    const float* b2_1   = (const float*)d_in[11];
    const float* g_t    = (const float*)d_in[12];
    const float* g1_0   = (const float*)d_in[13];
    const float* g2_0   = (const float*)d_in[14];
    const float* g1_1   = (const float*)d_in[15];
    const float* g2_1   = (const float*)d_in[16];
    const float* beta_t  = (const float*)d_in[17];
    const float* beta1_0 = (const float*)d_in[18];
    const float* beta2_0 = (const float*)d_in[19];
    const float* beta1_1 = (const float*)d_in[20];
    const float* beta2_1 = (const float*)d_in[21];

    float* out = (float*)d_out;

    float* buf0  = (float*)d_ws;
    float* buf1  = buf0 + (size_t)NC*NP;
    float* buf2  = buf1 + (size_t)NC*NP;
    float* nxyz  = buf2 + (size_t)NC*NP;                 // NB*NS*3
    int*   kidx  = (int*)(nxyz + (size_t)NB*NS*3);       // NP ints
    float* partials = (float*)(kidx + NP);               // 4096 floats
    float* affx  = partials + 4096;                      // 5*128

    fps_kernel<<<NB, 512, 0, stream>>>(xyz, out, nxyz);
    knn_kernel<<<NQ/4, 256, 0, stream>>>(xyz, nxyz, kidx);
    gather_kernel<<<NP/256, 256, 0, stream>>>(features, kidx, buf0);

    // stage t
    conv_kernel<<<NP/1024, 512, 0, stream>>>(buf0, buf1, w_t, b_t, affx, 0);
    stats_kernel<<<2048, 256, 0, stream>>>(buf1, partials);
    finalize_kernel<<<1, 64, 0, stream>>>(partials, g_t, beta_t, affx + 0);
    // resblock 0
    conv_kernel<<<NP/1024, 512, 0, stream>>>(buf1, buf0, w1_0, b1_0, affx + 0, 1);
    stats_kernel<<<2048, 256, 0, stream>>>(buf0, partials);
    finalize_kernel<<<1, 64, 0, stream>>>(partials, g1_0, beta1_0, affx + 128);
    conv_kernel<<<NP/1024, 512, 0, stream>>>(buf0, buf2, w2_0, b2_0, affx + 128, 1);
    stats_kernel<<<2048, 256, 0, stream>>>(buf2, partials);
    finalize_kernel<<<1, 64, 0, stream>>>(partials, g2_0, beta2_0, affx + 256);
    resid_kernel<<<(NC*NP/4)/256, 256, 0, stream>>>(buf2, buf1, buf0, affx + 256, affx + 0);
    // resblock 1
    conv_kernel<<<NP/1024, 512, 0, stream>>>(buf0, buf1, w1_1, b1_1, affx, 0);
    stats_kernel<<<2048, 256, 0, stream>>>(buf1, partials);
    finalize_kernel<<<1, 64, 0, stream>>>(partials, g1_1, beta1_1, affx + 384);
    conv_kernel<<<NP/1024, 512, 0, stream>>>(buf1, buf2, w2_1, b2_1, affx + 384, 1);
    stats_kernel<<<2048, 256, 0, stream>>>(buf2, partials);
    finalize_kernel<<<1, 64, 0, stream>>>(partials, g2_1, beta2_1, affx + 512);
    // epilogue: residual + max over K
    final_kernel<<<(NC*NQ)/256, 256, 0, stream>>>(buf2, buf0, affx + 512, out + (size_t)NB*3*NS);
}